// Round 5
// baseline (4940.531 us; speedup 1.0000x reference)
//
#include <hip/hip_runtime.h>
#include <math.h>

#define N_NODES 100000
#define N_EDGES 1600000
#define N_FEATS 128
#define HIDDEN 20
#define N_GRAPHS 256

// Static device scratch (fully overwritten each call before any read).
__device__ float g_y[(size_t)N_NODES * HIDDEN];    // 8 MB
__device__ float g_acc[(size_t)N_NODES * HIDDEN];  // 8 MB

// ---- inline index-dtype detection -------------------------------------------
// If edge_index is int64 (values < 2^31), every odd int32 word is 0.
__device__ __forceinline__ int detect_is64(const int* __restrict__ e32) {
    int acc = 0;
    #pragma unroll
    for (int j = 0; j < 8; j++) {
        int k = j * (N_EDGES / 8) + 997 * j + 13;
        acc |= e32[2 * k + 1];
    }
    return acc == 0;
}

// ---------------- mm1: g_y = x @ W1 ; g_acc = g_y ----------------------------
__global__ __launch_bounds__(256) void mm1_kernel(const float* __restrict__ x,
                                                  const float* __restrict__ W) {  // 128x20
    __shared__ float ldsW[N_FEATS * HIDDEN];
    __shared__ float ldsX[64 * (N_FEATS + 1)];
    const int t = threadIdx.x;
    for (int i = t; i < N_FEATS * HIDDEN; i += 256) ldsW[i] = W[i];
    const int rowBase = blockIdx.x * 64;
    for (int i = t; i < 64 * (N_FEATS / 4); i += 256) {
        int r = i >> 5;
        int kc = i & 31;
        float4 v = make_float4(0.f, 0.f, 0.f, 0.f);
        int grow = rowBase + r;
        if (grow < N_NODES) v = ((const float4*)x)[(size_t)grow * (N_FEATS / 4) + kc];
        int base = r * (N_FEATS + 1) + kc * 4;
        ldsX[base + 0] = v.x; ldsX[base + 1] = v.y;
        ldsX[base + 2] = v.z; ldsX[base + 3] = v.w;
    }
    __syncthreads();
    const int r = t & 63;
    const int cbase = (t >> 6) * 5;
    float a0 = 0.f, a1 = 0.f, a2 = 0.f, a3 = 0.f, a4 = 0.f;
    #pragma unroll 4
    for (int k = 0; k < N_FEATS; k++) {
        float xv = ldsX[r * (N_FEATS + 1) + k];
        const float* w = &ldsW[k * HIDDEN + cbase];
        a0 = fmaf(xv, w[0], a0);
        a1 = fmaf(xv, w[1], a1);
        a2 = fmaf(xv, w[2], a2);
        a3 = fmaf(xv, w[3], a3);
        a4 = fmaf(xv, w[4], a4);
    }
    const int grow = rowBase + r;
    if (grow < N_NODES) {
        float* yp = &g_y[(size_t)grow * HIDDEN + cbase];
        float* ap = &g_acc[(size_t)grow * HIDDEN + cbase];
        yp[0] = a0; yp[1] = a1; yp[2] = a2; yp[3] = a3; yp[4] = a4;
        ap[0] = a0; ap[1] = a1; ap[2] = a2; ap[3] = a3; ap[4] = a4;
    }
}

// ------- mm_small: h = relu(g_acc + bPrev); g_y = h@W ; g_acc = g_y ----------
__global__ __launch_bounds__(256) void mm_small_kernel(const float* __restrict__ bPrev,
                                                       const float* __restrict__ W) {  // 20x20
    __shared__ float ldsW[HIDDEN * HIDDEN];
    __shared__ float ldsB[HIDDEN];
    const int t = threadIdx.x;
    // BUG FIX (R1-R4): HIDDEN*HIDDEN = 400 > 256 threads -> strided load,
    // previously ldsW[256..399] was uninitialized garbage.
    for (int i = t; i < HIDDEN * HIDDEN; i += 256) ldsW[i] = W[i];
    if (t < HIDDEN) ldsB[t] = bPrev[t];
    __syncthreads();
    const int node = blockIdx.x * 256 + t;
    if (node >= N_NODES) return;
    const float4* rp = (const float4*)&g_acc[(size_t)node * HIDDEN];
    float4 q0 = rp[0], q1 = rp[1], q2 = rp[2], q3 = rp[3], q4 = rp[4];
    float h[HIDDEN] = {q0.x, q0.y, q0.z, q0.w, q1.x, q1.y, q1.z, q1.w,
                       q2.x, q2.y, q2.z, q2.w, q3.x, q3.y, q3.z, q3.w,
                       q4.x, q4.y, q4.z, q4.w};
    #pragma unroll
    for (int c = 0; c < HIDDEN; c++) {
        float v = h[c] + ldsB[c];
        h[c] = v > 0.f ? v : 0.f;
    }
    float outv[HIDDEN];
    #pragma unroll
    for (int c = 0; c < HIDDEN; c++) {
        float s = 0.f;
        #pragma unroll
        for (int k = 0; k < HIDDEN; k++) s = fmaf(h[k], ldsW[k * HIDDEN + c], s);
        outv[c] = s;
    }
    float* yp = &g_y[(size_t)node * HIDDEN];
    float* ap = &g_acc[(size_t)node * HIDDEN];
    #pragma unroll
    for (int c = 0; c < HIDDEN; c++) { yp[c] = outv[c]; ap[c] = outv[c]; }
}

// ---------------- edge: g_acc[dst] += g_y[src]  (atomics baseline) -----------
__global__ __launch_bounds__(256) void edge_kernel(const void* __restrict__ eidx) {
    const int e = blockIdx.x * 256 + threadIdx.x;
    if (e >= N_EDGES) return;
    const int* e32 = (const int*)eidx;
    int s, d;
    if (detect_is64(e32)) {
        const long long* e64 = (const long long*)eidx;
        s = (int)e64[e];
        d = (int)e64[N_EDGES + e];
    } else {
        s = e32[e];
        d = e32[N_EDGES + e];
    }
    if ((unsigned)s >= N_NODES || (unsigned)d >= N_NODES) return;
    const float4* yp = (const float4*)&g_y[(size_t)s * HIDDEN];
    float* ap = &g_acc[(size_t)d * HIDDEN];
    #pragma unroll
    for (int j = 0; j < 5; j++) {
        float4 v = yp[j];
        atomicAdd(ap + j * 4 + 0, v.x);
        atomicAdd(ap + j * 4 + 1, v.y);
        atomicAdd(ap + j * 4 + 2, v.z);
        atomicAdd(ap + j * 4 + 3, v.w);
    }
}

// ---------------- pool + final linear ----------------------------------------
__global__ __launch_bounds__(256) void pool_kernel(const float* __restrict__ b3,
                                                   const void* __restrict__ batch,
                                                   const void* __restrict__ eidx,
                                                   const float* __restrict__ Wl,  // 40x2
                                                   const float* __restrict__ bl,  // 2
                                                   float* __restrict__ out) {
    const int g = blockIdx.x;
    const int t = threadIdx.x;
    const int is64 = detect_is64((const int*)eidx);
    const int* b32 = (const int*)batch;
    const long long* b64 = (const long long*)batch;
    #define BAT(i) (is64 ? (int)b64[i] : b32[i])

    int lo = 0, hi = N_NODES;
    while (lo < hi) { int mid = (lo + hi) >> 1; if (BAT(mid) < g) lo = mid + 1; else hi = mid; }
    const int start = lo;
    lo = start; hi = N_NODES;
    while (lo < hi) { int mid = (lo + hi) >> 1; if (BAT(mid) < g + 1) lo = mid + 1; else hi = mid; }
    const int end = lo;
    #undef BAT

    float b3r[HIDDEN];
    #pragma unroll
    for (int c = 0; c < HIDDEN; c++) b3r[c] = b3[c];

    float mx[HIDDEN], sm[HIDDEN];
    #pragma unroll
    for (int c = 0; c < HIDDEN; c++) { mx[c] = 0.f; sm[c] = 0.f; }  // relu >= 0

    for (int i = start + t; i < end; i += 256) {
        const float4* rp = (const float4*)&g_acc[(size_t)i * HIDDEN];
        float4 q[5] = {rp[0], rp[1], rp[2], rp[3], rp[4]};
        const float* r = (const float*)q;
        #pragma unroll
        for (int c = 0; c < HIDDEN; c++) {
            float v = r[c] + b3r[c];
            v = v > 0.f ? v : 0.f;
            mx[c] = fmaxf(mx[c], v);
            sm[c] += v;
        }
    }
    #pragma unroll
    for (int off = 32; off >= 1; off >>= 1) {
        #pragma unroll
        for (int c = 0; c < HIDDEN; c++) {
            mx[c] = fmaxf(mx[c], __shfl_xor(mx[c], off));
            sm[c] += __shfl_xor(sm[c], off);
        }
    }
    __shared__ float smx[4][HIDDEN];
    __shared__ float ssm[4][HIDDEN];
    const int wave = t >> 6, lane = t & 63;
    if (lane == 0) {
        #pragma unroll
        for (int c = 0; c < HIDDEN; c++) { smx[wave][c] = mx[c]; ssm[wave][c] = sm[c]; }
    }
    __syncthreads();
    if (t == 0) {
        float cnt = (float)(end - start);
        float pooled[2 * HIDDEN];
        #pragma unroll
        for (int c = 0; c < HIDDEN; c++) {
            float m = smx[0][c], s = ssm[0][c];
            #pragma unroll
            for (int w = 1; w < 4; w++) { m = fmaxf(m, smx[w][c]); s += ssm[w][c]; }
            pooled[c] = m;
            pooled[HIDDEN + c] = s / fmaxf(cnt, 1.f);
        }
        #pragma unroll
        for (int c = 0; c < 2; c++) {
            float o = bl[c];
            #pragma unroll
            for (int k = 0; k < 2 * HIDDEN; k++) o = fmaf(pooled[k], Wl[k * 2 + c], o);
            out[g * 2 + c] = o;
        }
    }
}

extern "C" void kernel_launch(void* const* d_in, const int* in_sizes, int n_in,
                              void* d_out, int out_size, void* d_ws, size_t ws_size,
                              hipStream_t stream) {
    const float* x    = (const float*)d_in[0];
    const void* eidx  = d_in[1];
    const void* batch = d_in[2];
    const float* W1  = (const float*)d_in[3];
    const float* b1  = (const float*)d_in[4];
    const float* W2  = (const float*)d_in[5];
    const float* b2  = (const float*)d_in[6];
    const float* W3  = (const float*)d_in[7];
    const float* b3  = (const float*)d_in[8];
    const float* Wl  = (const float*)d_in[9];
    const float* bl  = (const float*)d_in[10];
    float* out = (float*)d_out;
    (void)d_ws; (void)ws_size;

    const int mm1_blocks  = (N_NODES + 63) / 64;
    const int node_blocks = (N_NODES + 255) / 256;
    const int edge_blocks = (N_EDGES + 255) / 256;

    mm1_kernel<<<mm1_blocks, 256, 0, stream>>>(x, W1);
    edge_kernel<<<edge_blocks, 256, 0, stream>>>(eidx);
    mm_small_kernel<<<node_blocks, 256, 0, stream>>>(b1, W2);
    edge_kernel<<<edge_blocks, 256, 0, stream>>>(eidx);
    mm_small_kernel<<<node_blocks, 256, 0, stream>>>(b2, W3);
    edge_kernel<<<edge_blocks, 256, 0, stream>>>(eidx);
    pool_kernel<<<N_GRAPHS, 256, 0, stream>>>(b3, batch, eidx, Wl, bl, out);
}

// Round 6
// 641.965 us; speedup vs baseline: 7.6960x; 7.6960x over previous
//
#include <hip/hip_runtime.h>
#include <math.h>

#define N_NODES 100000
#define N_EDGES 1600000
#define N_FEATS 128
#define HIDDEN 20
#define N_GRAPHS 256

// Static device scratch (all fully rewritten each call before any read).
__device__ float g_y[(size_t)N_NODES * HIDDEN];    // 8 MB
__device__ float g_acc[(size_t)N_NODES * HIDDEN];  // 8 MB
__device__ int   g_cnt[N_NODES];                   // per-dst degree
__device__ int   g_rowptr[N_NODES + 1];            // CSR row pointers
__device__ int   g_cursor[N_NODES];                // scatter cursors
__device__ int   g_col[N_EDGES];                   // CSR src indices

// ---- inline index-dtype detection (int64 edge_index has zero odd words) -----
__device__ __forceinline__ int detect_is64(const int* __restrict__ e32) {
    int acc = 0;
    #pragma unroll
    for (int j = 0; j < 8; j++) {
        int k = j * (N_EDGES / 8) + 997 * j + 13;
        acc |= e32[2 * k + 1];
    }
    return acc == 0;
}

__device__ __forceinline__ void load_edge(const void* eidx, int is64, int e,
                                          int& s, int& d) {
    if (is64) {
        const long long* e64 = (const long long*)eidx;
        s = (int)e64[e];
        d = (int)e64[N_EDGES + e];
    } else {
        const int* e32 = (const int*)eidx;
        s = e32[e];
        d = e32[N_EDGES + e];
    }
}

// ---------------- CSR build ---------------------------------------------------
__global__ __launch_bounds__(256) void zero_kernel() {
    const int i = blockIdx.x * 256 + threadIdx.x;
    if (i < N_NODES) g_cnt[i] = 0;
}

__global__ __launch_bounds__(256) void hist_kernel(const void* __restrict__ eidx) {
    const int e = blockIdx.x * 256 + threadIdx.x;
    if (e >= N_EDGES) return;
    const int is64 = detect_is64((const int*)eidx);
    int s, d;
    load_edge(eidx, is64, e, s, d);
    if ((unsigned)d >= N_NODES) return;
    atomicAdd(&g_cnt[d], 1);
}

#define SCAN_THREADS 1024
__global__ __launch_bounds__(SCAN_THREADS) void scan_kernel() {
    __shared__ int partial[SCAN_THREADS];
    const int t = threadIdx.x;
    const int CHUNK = (N_NODES + SCAN_THREADS - 1) / SCAN_THREADS;  // 98
    const int base = t * CHUNK;
    int sum = 0;
    for (int i = 0; i < CHUNK; i++) {
        int idx = base + i;
        if (idx < N_NODES) sum += g_cnt[idx];
    }
    partial[t] = sum;
    __syncthreads();
    for (int off = 1; off < SCAN_THREADS; off <<= 1) {
        int v = (t >= off) ? partial[t - off] : 0;
        __syncthreads();
        partial[t] += v;
        __syncthreads();
    }
    int run = (t == 0) ? 0 : partial[t - 1];
    for (int i = 0; i < CHUNK; i++) {
        int idx = base + i;
        if (idx < N_NODES) {
            g_rowptr[idx] = run;
            g_cursor[idx] = run;
            run += g_cnt[idx];
        }
    }
    if (t == SCAN_THREADS - 1) g_rowptr[N_NODES] = run;
}

__global__ __launch_bounds__(256) void scatter_kernel(const void* __restrict__ eidx) {
    const int e = blockIdx.x * 256 + threadIdx.x;
    if (e >= N_EDGES) return;
    const int is64 = detect_is64((const int*)eidx);
    int s, d;
    load_edge(eidx, is64, e, s, d);
    if ((unsigned)s >= N_NODES || (unsigned)d >= N_NODES) return;
    int pos = atomicAdd(&g_cursor[d], 1);
    g_col[pos] = s;
}

// ---------------- mm1: g_y = x @ W1 ; g_acc = g_y ----------------------------
__global__ __launch_bounds__(256) void mm1_kernel(const float* __restrict__ x,
                                                  const float* __restrict__ W) {  // 128x20
    __shared__ float ldsW[N_FEATS * HIDDEN];
    __shared__ float ldsX[64 * (N_FEATS + 1)];
    const int t = threadIdx.x;
    for (int i = t; i < N_FEATS * HIDDEN; i += 256) ldsW[i] = W[i];
    const int rowBase = blockIdx.x * 64;
    for (int i = t; i < 64 * (N_FEATS / 4); i += 256) {
        int r = i >> 5;
        int kc = i & 31;
        float4 v = make_float4(0.f, 0.f, 0.f, 0.f);
        int grow = rowBase + r;
        if (grow < N_NODES) v = ((const float4*)x)[(size_t)grow * (N_FEATS / 4) + kc];
        int base = r * (N_FEATS + 1) + kc * 4;
        ldsX[base + 0] = v.x; ldsX[base + 1] = v.y;
        ldsX[base + 2] = v.z; ldsX[base + 3] = v.w;
    }
    __syncthreads();
    const int r = t & 63;
    const int cbase = (t >> 6) * 5;
    float a0 = 0.f, a1 = 0.f, a2 = 0.f, a3 = 0.f, a4 = 0.f;
    #pragma unroll 4
    for (int k = 0; k < N_FEATS; k++) {
        float xv = ldsX[r * (N_FEATS + 1) + k];
        const float* w = &ldsW[k * HIDDEN + cbase];
        a0 = fmaf(xv, w[0], a0);
        a1 = fmaf(xv, w[1], a1);
        a2 = fmaf(xv, w[2], a2);
        a3 = fmaf(xv, w[3], a3);
        a4 = fmaf(xv, w[4], a4);
    }
    const int grow = rowBase + r;
    if (grow < N_NODES) {
        float* yp = &g_y[(size_t)grow * HIDDEN + cbase];
        float* ap = &g_acc[(size_t)grow * HIDDEN + cbase];
        yp[0] = a0; yp[1] = a1; yp[2] = a2; yp[3] = a3; yp[4] = a4;
        ap[0] = a0; ap[1] = a1; ap[2] = a2; ap[3] = a3; ap[4] = a4;
    }
}

// ------- mm_small: h = relu(g_acc + bPrev); g_y = h@W ; g_acc = g_y ----------
__global__ __launch_bounds__(256) void mm_small_kernel(const float* __restrict__ bPrev,
                                                       const float* __restrict__ W) {  // 20x20
    __shared__ float ldsW[HIDDEN * HIDDEN];
    __shared__ float ldsB[HIDDEN];
    const int t = threadIdx.x;
    for (int i = t; i < HIDDEN * HIDDEN; i += 256) ldsW[i] = W[i];  // 400 > 256!
    if (t < HIDDEN) ldsB[t] = bPrev[t];
    __syncthreads();
    const int node = blockIdx.x * 256 + t;
    if (node >= N_NODES) return;
    const float4* rp = (const float4*)&g_acc[(size_t)node * HIDDEN];
    float4 q0 = rp[0], q1 = rp[1], q2 = rp[2], q3 = rp[3], q4 = rp[4];
    float h[HIDDEN] = {q0.x, q0.y, q0.z, q0.w, q1.x, q1.y, q1.z, q1.w,
                       q2.x, q2.y, q2.z, q2.w, q3.x, q3.y, q3.z, q3.w,
                       q4.x, q4.y, q4.z, q4.w};
    #pragma unroll
    for (int c = 0; c < HIDDEN; c++) {
        float v = h[c] + ldsB[c];
        h[c] = v > 0.f ? v : 0.f;
    }
    float outv[HIDDEN];
    #pragma unroll
    for (int c = 0; c < HIDDEN; c++) {
        float s = 0.f;
        #pragma unroll
        for (int k = 0; k < HIDDEN; k++) s = fmaf(h[k], ldsW[k * HIDDEN + c], s);
        outv[c] = s;
    }
    float* yp = &g_y[(size_t)node * HIDDEN];
    float* ap = &g_acc[(size_t)node * HIDDEN];
    #pragma unroll
    for (int c = 0; c < HIDDEN; c++) { yp[c] = outv[c]; ap[c] = outv[c]; }
}

// ------- gather: g_acc[n][chunk] += sum_{s in CSR(n)} g_y[s][chunk] ----------
// Thread per (node, float4 chunk): 500K threads, no atomics.
__global__ __launch_bounds__(256) void gather_kernel() {
    const int tid = blockIdx.x * 256 + threadIdx.x;
    if (tid >= N_NODES * 5) return;
    const int node = tid / 5;
    const int chunk = tid - node * 5;
    const int beg = g_rowptr[node];
    const int end = g_rowptr[node + 1];
    float4 sum = make_float4(0.f, 0.f, 0.f, 0.f);
    for (int i = beg; i < end; i++) {
        const int s = g_col[i];
        float4 v = *(const float4*)&g_y[(size_t)s * HIDDEN + chunk * 4];
        sum.x += v.x; sum.y += v.y; sum.z += v.z; sum.w += v.w;
    }
    float4* ap = (float4*)&g_acc[(size_t)node * HIDDEN + chunk * 4];
    float4 a = *ap;
    a.x += sum.x; a.y += sum.y; a.z += sum.z; a.w += sum.w;
    *ap = a;
}

// ---------------- pool + final linear ----------------------------------------
__global__ __launch_bounds__(256) void pool_kernel(const float* __restrict__ b3,
                                                   const void* __restrict__ batch,
                                                   const void* __restrict__ eidx,
                                                   const float* __restrict__ Wl,  // 40x2
                                                   const float* __restrict__ bl,  // 2
                                                   float* __restrict__ out) {
    const int g = blockIdx.x;
    const int t = threadIdx.x;
    const int is64 = detect_is64((const int*)eidx);
    const int* b32 = (const int*)batch;
    const long long* b64 = (const long long*)batch;
    #define BAT(i) (is64 ? (int)b64[i] : b32[i])
    int lo = 0, hi = N_NODES;
    while (lo < hi) { int mid = (lo + hi) >> 1; if (BAT(mid) < g) lo = mid + 1; else hi = mid; }
    const int start = lo;
    lo = start; hi = N_NODES;
    while (lo < hi) { int mid = (lo + hi) >> 1; if (BAT(mid) < g + 1) lo = mid + 1; else hi = mid; }
    const int end = lo;
    #undef BAT

    float b3r[HIDDEN];
    #pragma unroll
    for (int c = 0; c < HIDDEN; c++) b3r[c] = b3[c];
    float mx[HIDDEN], sm[HIDDEN];
    #pragma unroll
    for (int c = 0; c < HIDDEN; c++) { mx[c] = 0.f; sm[c] = 0.f; }  // relu >= 0

    for (int i = start + t; i < end; i += 256) {
        const float4* rp = (const float4*)&g_acc[(size_t)i * HIDDEN];
        float4 q[5] = {rp[0], rp[1], rp[2], rp[3], rp[4]};
        const float* r = (const float*)q;
        #pragma unroll
        for (int c = 0; c < HIDDEN; c++) {
            float v = r[c] + b3r[c];
            v = v > 0.f ? v : 0.f;
            mx[c] = fmaxf(mx[c], v);
            sm[c] += v;
        }
    }
    #pragma unroll
    for (int off = 32; off >= 1; off >>= 1) {
        #pragma unroll
        for (int c = 0; c < HIDDEN; c++) {
            mx[c] = fmaxf(mx[c], __shfl_xor(mx[c], off));
            sm[c] += __shfl_xor(sm[c], off);
        }
    }
    __shared__ float smx[4][HIDDEN];
    __shared__ float ssm[4][HIDDEN];
    const int wave = t >> 6, lane = t & 63;
    if (lane == 0) {
        #pragma unroll
        for (int c = 0; c < HIDDEN; c++) { smx[wave][c] = mx[c]; ssm[wave][c] = sm[c]; }
    }
    __syncthreads();
    if (t == 0) {
        float cnt = (float)(end - start);
        float pooled[2 * HIDDEN];
        #pragma unroll
        for (int c = 0; c < HIDDEN; c++) {
            float m = smx[0][c], s = ssm[0][c];
            #pragma unroll
            for (int w = 1; w < 4; w++) { m = fmaxf(m, smx[w][c]); s += ssm[w][c]; }
            pooled[c] = m;
            pooled[HIDDEN + c] = s / fmaxf(cnt, 1.f);
        }
        #pragma unroll
        for (int c = 0; c < 2; c++) {
            float o = bl[c];
            #pragma unroll
            for (int k = 0; k < 2 * HIDDEN; k++) o = fmaf(pooled[k], Wl[k * 2 + c], o);
            out[g * 2 + c] = o;
        }
    }
}

extern "C" void kernel_launch(void* const* d_in, const int* in_sizes, int n_in,
                              void* d_out, int out_size, void* d_ws, size_t ws_size,
                              hipStream_t stream) {
    const float* x    = (const float*)d_in[0];
    const void* eidx  = d_in[1];
    const void* batch = d_in[2];
    const float* W1  = (const float*)d_in[3];
    const float* b1  = (const float*)d_in[4];
    const float* W2  = (const float*)d_in[5];
    const float* b2  = (const float*)d_in[6];
    const float* W3  = (const float*)d_in[7];
    const float* b3  = (const float*)d_in[8];
    const float* Wl  = (const float*)d_in[9];
    const float* bl  = (const float*)d_in[10];
    float* out = (float*)d_out;
    (void)d_ws; (void)ws_size;

    const int node_blocks   = (N_NODES + 255) / 256;          // 391
    const int edge_blocks   = (N_EDGES + 255) / 256;          // 6250
    const int mm1_blocks    = (N_NODES + 63) / 64;            // 1563
    const int gather_blocks = (N_NODES * 5 + 255) / 256;      // 1954

    // CSR build (once, reused 3x)
    zero_kernel<<<node_blocks, 256, 0, stream>>>();
    hist_kernel<<<edge_blocks, 256, 0, stream>>>(eidx);
    scan_kernel<<<1, SCAN_THREADS, 0, stream>>>();
    scatter_kernel<<<edge_blocks, 256, 0, stream>>>(eidx);

    // layer 1
    mm1_kernel<<<mm1_blocks, 256, 0, stream>>>(x, W1);
    gather_kernel<<<gather_blocks, 256, 0, stream>>>();
    // layer 2
    mm_small_kernel<<<node_blocks, 256, 0, stream>>>(b1, W2);
    gather_kernel<<<gather_blocks, 256, 0, stream>>>();
    // layer 3
    mm_small_kernel<<<node_blocks, 256, 0, stream>>>(b2, W3);
    gather_kernel<<<gather_blocks, 256, 0, stream>>>();
    // pool + final linear
    pool_kernel<<<N_GRAPHS, 256, 0, stream>>>(b3, batch, eidx, Wl, bl, out);
}

// Round 7
// 381.762 us; speedup vs baseline: 12.9414x; 1.6816x over previous
//
#include <hip/hip_runtime.h>
#include <math.h>

#define N_NODES 100000
#define N_EDGES 1600000
#define N_FEATS 128
#define HIDDEN 20
#define N_GRAPHS 256

#define NODE_BLOCKS ((N_NODES + 255) / 256)   // 391

// Static device scratch (all fully rewritten each call before any read).
__device__ float g_y[(size_t)N_NODES * HIDDEN];    // 8 MB
__device__ float g_acc[(size_t)N_NODES * HIDDEN];  // 8 MB
__device__ int   g_cnt[N_NODES];
__device__ int   g_rowptr[N_NODES + 1];
__device__ int   g_cursor[N_NODES];
__device__ int   g_col[N_EDGES];
__device__ int   g_blocksum[NODE_BLOCKS];
__device__ int   g_blockoff[NODE_BLOCKS];

// ---- inline index-dtype detection (int64 edge_index has zero odd words) -----
__device__ __forceinline__ int detect_is64(const int* __restrict__ e32) {
    int acc = 0;
    #pragma unroll
    for (int j = 0; j < 8; j++) {
        int k = j * (N_EDGES / 8) + 997 * j + 13;
        acc |= e32[2 * k + 1];
    }
    return acc == 0;
}

__device__ __forceinline__ void load_edge(const void* eidx, int is64, int e,
                                          int& s, int& d) {
    if (is64) {
        const long long* e64 = (const long long*)eidx;
        s = (int)e64[e];
        d = (int)e64[N_EDGES + e];
    } else {
        const int* e32 = (const int*)eidx;
        s = e32[e];
        d = e32[N_EDGES + e];
    }
}

// ---------------- CSR build ---------------------------------------------------
__global__ __launch_bounds__(256) void zero_kernel() {
    const int i = blockIdx.x * 256 + threadIdx.x;
    if (i < N_NODES) g_cnt[i] = 0;
}

__global__ __launch_bounds__(256) void hist_kernel(const void* __restrict__ eidx) {
    const int e = blockIdx.x * 256 + threadIdx.x;
    if (e >= N_EDGES) return;
    const int is64 = detect_is64((const int*)eidx);
    int s, d;
    load_edge(eidx, is64, e, s, d);
    if ((unsigned)d >= N_NODES) return;
    atomicAdd(&g_cnt[d], 1);
}

// pass 1: per-block sums of g_cnt (coalesced)
__global__ __launch_bounds__(256) void blocksum_kernel() {
    const int t = threadIdx.x;
    const int i = blockIdx.x * 256 + t;
    int v = (i < N_NODES) ? g_cnt[i] : 0;
    #pragma unroll
    for (int off = 32; off >= 1; off >>= 1) v += __shfl_xor(v, off);
    __shared__ int ws[4];
    if ((t & 63) == 0) ws[t >> 6] = v;
    __syncthreads();
    if (t == 0) g_blocksum[blockIdx.x] = ws[0] + ws[1] + ws[2] + ws[3];
}

// pass 2: exclusive scan of 391 block sums (single small block)
__global__ __launch_bounds__(512) void scanblocks_kernel() {
    __shared__ int lds[512];
    const int t = threadIdx.x;
    int v = (t < NODE_BLOCKS) ? g_blocksum[t] : 0;
    lds[t] = v;
    __syncthreads();
    for (int off = 1; off < 512; off <<= 1) {
        int u = (t >= off) ? lds[t - off] : 0;
        __syncthreads();
        lds[t] += u;
        __syncthreads();
    }
    if (t < NODE_BLOCKS) g_blockoff[t] = lds[t] - v;   // exclusive
    if (t == NODE_BLOCKS - 1) g_rowptr[N_NODES] = lds[t];
}

// pass 3: intra-block exclusive scan + block offset -> rowptr & cursor
__global__ __launch_bounds__(256) void scanfinal_kernel() {
    __shared__ int lds[256];
    const int t = threadIdx.x;
    const int i = blockIdx.x * 256 + t;
    int v = (i < N_NODES) ? g_cnt[i] : 0;
    lds[t] = v;
    __syncthreads();
    for (int off = 1; off < 256; off <<= 1) {
        int u = (t >= off) ? lds[t - off] : 0;
        __syncthreads();
        lds[t] += u;
        __syncthreads();
    }
    if (i < N_NODES) {
        int r = g_blockoff[blockIdx.x] + lds[t] - v;   // exclusive prefix
        g_rowptr[i] = r;
        g_cursor[i] = r;
    }
}

__global__ __launch_bounds__(256) void scatter_kernel(const void* __restrict__ eidx) {
    const int e = blockIdx.x * 256 + threadIdx.x;
    if (e >= N_EDGES) return;
    const int is64 = detect_is64((const int*)eidx);
    int s, d;
    load_edge(eidx, is64, e, s, d);
    if ((unsigned)s >= N_NODES || (unsigned)d >= N_NODES) return;
    int pos = atomicAdd(&g_cursor[d], 1);
    g_col[pos] = s;
}

// ---------------- mm1: g_y = x @ W1 ; g_acc = g_y ----------------------------
__global__ __launch_bounds__(256) void mm1_kernel(const float* __restrict__ x,
                                                  const float* __restrict__ W) {  // 128x20
    __shared__ float ldsW[N_FEATS * HIDDEN];
    __shared__ float ldsX[64 * (N_FEATS + 1)];
    const int t = threadIdx.x;
    for (int i = t; i < N_FEATS * HIDDEN; i += 256) ldsW[i] = W[i];
    const int rowBase = blockIdx.x * 64;
    for (int i = t; i < 64 * (N_FEATS / 4); i += 256) {
        int r = i >> 5;
        int kc = i & 31;
        float4 v = make_float4(0.f, 0.f, 0.f, 0.f);
        int grow = rowBase + r;
        if (grow < N_NODES) v = ((const float4*)x)[(size_t)grow * (N_FEATS / 4) + kc];
        int base = r * (N_FEATS + 1) + kc * 4;
        ldsX[base + 0] = v.x; ldsX[base + 1] = v.y;
        ldsX[base + 2] = v.z; ldsX[base + 3] = v.w;
    }
    __syncthreads();
    const int r = t & 63;
    const int cbase = (t >> 6) * 5;
    float a0 = 0.f, a1 = 0.f, a2 = 0.f, a3 = 0.f, a4 = 0.f;
    #pragma unroll 4
    for (int k = 0; k < N_FEATS; k++) {
        float xv = ldsX[r * (N_FEATS + 1) + k];
        const float* w = &ldsW[k * HIDDEN + cbase];
        a0 = fmaf(xv, w[0], a0);
        a1 = fmaf(xv, w[1], a1);
        a2 = fmaf(xv, w[2], a2);
        a3 = fmaf(xv, w[3], a3);
        a4 = fmaf(xv, w[4], a4);
    }
    const int grow = rowBase + r;
    if (grow < N_NODES) {
        float* yp = &g_y[(size_t)grow * HIDDEN + cbase];
        float* ap = &g_acc[(size_t)grow * HIDDEN + cbase];
        yp[0] = a0; yp[1] = a1; yp[2] = a2; yp[3] = a3; yp[4] = a4;
        ap[0] = a0; ap[1] = a1; ap[2] = a2; ap[3] = a3; ap[4] = a4;
    }
}

// ------- mm_small: h = relu(g_acc + bPrev); g_y = h@W ; g_acc = g_y ----------
__global__ __launch_bounds__(256) void mm_small_kernel(const float* __restrict__ bPrev,
                                                       const float* __restrict__ W) {  // 20x20
    __shared__ float ldsW[HIDDEN * HIDDEN];
    __shared__ float ldsB[HIDDEN];
    const int t = threadIdx.x;
    for (int i = t; i < HIDDEN * HIDDEN; i += 256) ldsW[i] = W[i];  // 400 > 256!
    if (t < HIDDEN) ldsB[t] = bPrev[t];
    __syncthreads();
    const int node = blockIdx.x * 256 + t;
    if (node >= N_NODES) return;
    const float4* rp = (const float4*)&g_acc[(size_t)node * HIDDEN];
    float4 q0 = rp[0], q1 = rp[1], q2 = rp[2], q3 = rp[3], q4 = rp[4];
    float h[HIDDEN] = {q0.x, q0.y, q0.z, q0.w, q1.x, q1.y, q1.z, q1.w,
                       q2.x, q2.y, q2.z, q2.w, q3.x, q3.y, q3.z, q3.w,
                       q4.x, q4.y, q4.z, q4.w};
    #pragma unroll
    for (int c = 0; c < HIDDEN; c++) {
        float v = h[c] + ldsB[c];
        h[c] = v > 0.f ? v : 0.f;
    }
    float outv[HIDDEN];
    #pragma unroll
    for (int c = 0; c < HIDDEN; c++) {
        float s = 0.f;
        #pragma unroll
        for (int k = 0; k < HIDDEN; k++) s = fmaf(h[k], ldsW[k * HIDDEN + c], s);
        outv[c] = s;
    }
    float* yp = &g_y[(size_t)node * HIDDEN];
    float* ap = &g_acc[(size_t)node * HIDDEN];
    #pragma unroll
    for (int c = 0; c < HIDDEN; c++) { yp[c] = outv[c]; ap[c] = outv[c]; }
}

// ------- gather: g_acc[n][chunk] += sum_{s in CSR(n)} g_y[s][chunk] ----------
__global__ __launch_bounds__(256) void gather_kernel() {
    const int tid = blockIdx.x * 256 + threadIdx.x;
    if (tid >= N_NODES * 5) return;
    const int node = tid / 5;
    const int chunk = tid - node * 5;
    const int beg = g_rowptr[node];
    const int end = g_rowptr[node + 1];
    float4 sum = make_float4(0.f, 0.f, 0.f, 0.f);
    for (int i = beg; i < end; i++) {
        const int s = g_col[i];
        float4 v = *(const float4*)&g_y[(size_t)s * HIDDEN + chunk * 4];
        sum.x += v.x; sum.y += v.y; sum.z += v.z; sum.w += v.w;
    }
    float4* ap = (float4*)&g_acc[(size_t)node * HIDDEN + chunk * 4];
    float4 a = *ap;
    a.x += sum.x; a.y += sum.y; a.z += sum.z; a.w += sum.w;
    *ap = a;
}

// ---------------- pool + final linear ----------------------------------------
__global__ __launch_bounds__(256) void pool_kernel(const float* __restrict__ b3,
                                                   const void* __restrict__ batch,
                                                   const void* __restrict__ eidx,
                                                   const float* __restrict__ Wl,  // 40x2
                                                   const float* __restrict__ bl,  // 2
                                                   float* __restrict__ out) {
    const int g = blockIdx.x;
    const int t = threadIdx.x;
    const int is64 = detect_is64((const int*)eidx);
    const int* b32 = (const int*)batch;
    const long long* b64 = (const long long*)batch;
    #define BAT(i) (is64 ? (int)b64[i] : b32[i])
    int lo = 0, hi = N_NODES;
    while (lo < hi) { int mid = (lo + hi) >> 1; if (BAT(mid) < g) lo = mid + 1; else hi = mid; }
    const int start = lo;
    lo = start; hi = N_NODES;
    while (lo < hi) { int mid = (lo + hi) >> 1; if (BAT(mid) < g + 1) lo = mid + 1; else hi = mid; }
    const int end = lo;
    #undef BAT

    float b3r[HIDDEN];
    #pragma unroll
    for (int c = 0; c < HIDDEN; c++) b3r[c] = b3[c];
    float mx[HIDDEN], sm[HIDDEN];
    #pragma unroll
    for (int c = 0; c < HIDDEN; c++) { mx[c] = 0.f; sm[c] = 0.f; }  // relu >= 0

    for (int i = start + t; i < end; i += 256) {
        const float4* rp = (const float4*)&g_acc[(size_t)i * HIDDEN];
        float4 q[5] = {rp[0], rp[1], rp[2], rp[3], rp[4]};
        const float* r = (const float*)q;
        #pragma unroll
        for (int c = 0; c < HIDDEN; c++) {
            float v = r[c] + b3r[c];
            v = v > 0.f ? v : 0.f;
            mx[c] = fmaxf(mx[c], v);
            sm[c] += v;
        }
    }
    #pragma unroll
    for (int off = 32; off >= 1; off >>= 1) {
        #pragma unroll
        for (int c = 0; c < HIDDEN; c++) {
            mx[c] = fmaxf(mx[c], __shfl_xor(mx[c], off));
            sm[c] += __shfl_xor(sm[c], off);
        }
    }
    __shared__ float smx[4][HIDDEN];
    __shared__ float ssm[4][HIDDEN];
    const int wave = t >> 6, lane = t & 63;
    if (lane == 0) {
        #pragma unroll
        for (int c = 0; c < HIDDEN; c++) { smx[wave][c] = mx[c]; ssm[wave][c] = sm[c]; }
    }
    __syncthreads();
    if (t == 0) {
        float cnt = (float)(end - start);
        float pooled[2 * HIDDEN];
        #pragma unroll
        for (int c = 0; c < HIDDEN; c++) {
            float m = smx[0][c], s = ssm[0][c];
            #pragma unroll
            for (int w = 1; w < 4; w++) { m = fmaxf(m, smx[w][c]); s += ssm[w][c]; }
            pooled[c] = m;
            pooled[HIDDEN + c] = s / fmaxf(cnt, 1.f);
        }
        #pragma unroll
        for (int c = 0; c < 2; c++) {
            float o = bl[c];
            #pragma unroll
            for (int k = 0; k < 2 * HIDDEN; k++) o = fmaf(pooled[k], Wl[k * 2 + c], o);
            out[g * 2 + c] = o;
        }
    }
}

extern "C" void kernel_launch(void* const* d_in, const int* in_sizes, int n_in,
                              void* d_out, int out_size, void* d_ws, size_t ws_size,
                              hipStream_t stream) {
    const float* x    = (const float*)d_in[0];
    const void* eidx  = d_in[1];
    const void* batch = d_in[2];
    const float* W1  = (const float*)d_in[3];
    const float* b1  = (const float*)d_in[4];
    const float* W2  = (const float*)d_in[5];
    const float* b2  = (const float*)d_in[6];
    const float* W3  = (const float*)d_in[7];
    const float* b3  = (const float*)d_in[8];
    const float* Wl  = (const float*)d_in[9];
    const float* bl  = (const float*)d_in[10];
    float* out = (float*)d_out;
    (void)d_ws; (void)ws_size;

    const int edge_blocks   = (N_EDGES + 255) / 256;          // 6250
    const int mm1_blocks    = (N_NODES + 63) / 64;            // 1563
    const int gather_blocks = (N_NODES * 5 + 255) / 256;      // 1954

    // CSR build (once, reused 3x)
    zero_kernel<<<NODE_BLOCKS, 256, 0, stream>>>();
    hist_kernel<<<edge_blocks, 256, 0, stream>>>(eidx);
    blocksum_kernel<<<NODE_BLOCKS, 256, 0, stream>>>();
    scanblocks_kernel<<<1, 512, 0, stream>>>();
    scanfinal_kernel<<<NODE_BLOCKS, 256, 0, stream>>>();
    scatter_kernel<<<edge_blocks, 256, 0, stream>>>(eidx);

    // layer 1
    mm1_kernel<<<mm1_blocks, 256, 0, stream>>>(x, W1);
    gather_kernel<<<gather_blocks, 256, 0, stream>>>();
    // layer 2
    mm_small_kernel<<<NODE_BLOCKS, 256, 0, stream>>>(b1, W2);
    gather_kernel<<<gather_blocks, 256, 0, stream>>>();
    // layer 3
    mm_small_kernel<<<NODE_BLOCKS, 256, 0, stream>>>(b2, W3);
    gather_kernel<<<gather_blocks, 256, 0, stream>>>();
    // pool + final linear
    pool_kernel<<<N_GRAPHS, 256, 0, stream>>>(b3, batch, eidx, Wl, bl, out);
}